// Round 18
// baseline (205.802 us; speedup 1.0000x reference)
//
#include <hip/hip_runtime.h>

#define N_NODES 10000
#define N_EDGES 640000
#define ELL_W   128    // max in-degree capacity; Poisson(64) => P(deg>127) ~ 1e-14
#define NB      157    // buckets of 64 nodes: bucket = dst >> 6
#define BCAP    4600   // per-bucket capacity (mean 4076, +8 sigma)
#define LCAP    80     // per-wg per-bucket LDS bin capacity (mean ~16, +16 sigma)
#define CHUNK   2500   // edges per workgroup in phase 1 (256 wgs * 2500 = 640000)

typedef short short8 __attribute__((ext_vector_type(8)));
typedef float f32x4 __attribute__((ext_vector_type(4)));

__device__ inline float bf2f(unsigned short u) {
    return __uint_as_float(((unsigned)u) << 16);
}
// round-to-nearest-even f32 -> bf16 (data here is never NaN)
__device__ inline unsigned short f2bf(float f) {
    unsigned u = __float_as_uint(f);
    u += 0x7fffu + ((u >> 16) & 1u);
    return (unsigned short)(u >> 16);
}

// ---------------------------------------------------------------------------
// Phase 1: bin edges by dst bucket (dst>>6) via LDS, coalesced flush.
// ---------------------------------------------------------------------------
__global__ __launch_bounds__(256) void bin_edges(const int* __restrict__ src,
                                                 const int* __restrict__ dst,
                                                 int* __restrict__ gCursor,
                                                 unsigned* __restrict__ gBucket) {
    __shared__ unsigned bins[NB][LCAP];
    __shared__ int cnt[NB];
    __shared__ int base[NB];
    int t = threadIdx.x;
    for (int i = t; i < NB; i += 256) cnt[i] = 0;
    __syncthreads();

    int e0 = blockIdx.x * CHUNK;
    int e1 = min(e0 + CHUNK, N_EDGES);
    for (int e = e0 + t; e < e1; e += 256) {
        int d = dst[e];
        int b = d >> 6;
        unsigned pk = ((unsigned)src[e] << 6) | (unsigned)(d & 63);
        int p = atomicAdd(&cnt[b], 1);
        if (p < LCAP) bins[b][p] = pk;
    }
    __syncthreads();
    for (int i = t; i < NB; i += 256) {
        int c = min(cnt[i], LCAP);
        cnt[i] = c;
        base[i] = atomicAdd(&gCursor[i], c);
    }
    __syncthreads();
    int wave = t >> 6, lane = t & 63;
    for (int b = wave; b < NB; b += 4) {
        int ba = base[b];
        int n = min(cnt[b], max(0, BCAP - ba));
        for (int i = lane; i < n; i += 64)
            gBucket[(size_t)b * BCAP + ba + i] = bins[b][i];
    }
}

// ---------------------------------------------------------------------------
// Phase 2: one workgroup per bucket; build 64 ELL rows in LDS, write coalesced.
// ---------------------------------------------------------------------------
__global__ __launch_bounds__(256) void build_ell(const unsigned* __restrict__ gBucket,
                                                 const int* __restrict__ gCursor,
                                                 unsigned short* __restrict__ ell,
                                                 int* __restrict__ deg) {
    __shared__ unsigned short rows[64 * ELL_W];  // 16 KB
    __shared__ int ldeg[64];
    int b = blockIdx.x;
    int t = threadIdx.x;
    for (int i = t; i < 64; i += 256) ldeg[i] = 0;
    __syncthreads();

    int n = min(gCursor[b], BCAP);
    const unsigned* bk = gBucket + (size_t)b * BCAP;
    for (int i = t; i < n; i += 256) {
        unsigned pk = bk[i];
        int local = pk & 63;
        int s = pk >> 6;
        int p = atomicAdd(&ldeg[local], 1);
        if (p < ELL_W) rows[local * ELL_W + p] = (unsigned short)s;
    }
    __syncthreads();

    int node0 = b * 64;
    int nNodes = min(64, N_NODES - node0);
    if (nNodes <= 0) return;
    for (int i = t; i < nNodes; i += 256)
        deg[node0 + i] = min(ldeg[i], ELL_W);
    int totalVec = nNodes * (ELL_W / 8);
    short8* dstv = (short8*)(ell + (size_t)node0 * ELL_W);
    const short8* srcv = (const short8*)rows;
    for (int i = t; i < totalVec; i += 256) dstv[i] = srcv[i];
}

// ---------------------------------------------------------------------------
// Combined prep: zero bucket cursors + cvt x fp32->bf16 + cvt/transpose weights
// ---------------------------------------------------------------------------
struct WList {
    const float* src[6];
    unsigned short* dst[6];
    int K[6];
    int off[7];  // element offsets, N == 256 for all
};

__global__ __launch_bounds__(256) void prep_kernel(const float4* __restrict__ x,
                                                   ushort4* __restrict__ xb, int n4,
                                                   WList wl, int totalW,
                                                   int* __restrict__ gCursor) {
    int idx = blockIdx.x * 256 + threadIdx.x;
    if (blockIdx.x == 0 && threadIdx.x < NB) gCursor[threadIdx.x] = 0;
    if (idx < n4) {
        float4 v = x[idx];
        ushort4 o;
        o.x = f2bf(v.x); o.y = f2bf(v.y); o.z = f2bf(v.z); o.w = f2bf(v.w);
        xb[idx] = o;
        return;
    }
    int r0 = idx - n4;
    if (r0 >= totalW) return;
    int w = 0;
    while (r0 >= wl.off[w + 1]) ++w;
    int r = r0 - wl.off[w];
    int k = r >> 8;          // N = 256
    int n = r & 255;
    wl.dst[w][(size_t)n * wl.K[w] + k] = f2bf(wl.src[w][r]);
}

// ---------------------------------------------------------------------------
// Fused GIN layer: agg(LDS) = gather(xin) ; hid = ReLU(agg@WtA+bA) ;
// out = hid@WtB+bB. INPUT AND OUTPUT MUST NOT ALIAS (r17 bug: in-place B2
// raced — block j overwrote rows block i was still gathering).
// Block = 256 thr = 4 waves, 16 nodes per block (625 blocks, 2500 waves).
// Gather phase keeps the r10-proven pattern: one wave-task = one node-half,
// 4 B/lane coalesced 256 B row reads, depth-16 load batches.
// MFMA fragment mapping (mfma_f32_16x16x32_bf16, HW-verified):
//   A: row = lane&15, k = (lane>>4)*8 + j ; B: col = lane&15, same k
//   D: col = lane&15, row = (lane>>4)*4 + reg
// ---------------------------------------------------------------------------
template <int K1, bool RELU2, bool F32OUT>
__global__ __launch_bounds__(256) void fused_gin(const unsigned* __restrict__ xu,
                                                 const unsigned short* __restrict__ ell,
                                                 const int* __restrict__ deg,
                                                 const unsigned short* __restrict__ WtA,
                                                 const float* __restrict__ biasA,
                                                 const unsigned short* __restrict__ WtB,
                                                 const float* __restrict__ biasB,
                                                 void* __restrict__ Cout) {
    constexpr int U2 = K1 / 2;        // uints per input row
    constexpr int NH = K1 / 128;      // 128-ch halves per row (1 or 2)
    constexpr int LPA = K1 + 8;       // agg pitch (ushort)
    constexpr int LPAU = LPA / 2;     // agg pitch (uint)
    constexpr int KSTEPS = K1 / 32;
    __shared__ unsigned short agg[16 * LPA];
    __shared__ unsigned short hid[16 * 264];

    int r0 = blockIdx.x * 16;         // 625*16 = 10000 exactly
    int tid = threadIdx.x;
    int lane = tid & 63;
    int wave = tid >> 6;

    // ---- Phase 0: aggregate 16 nodes into LDS (16*NH wave-tasks) ----
    unsigned* aggU = (unsigned*)agg;
    for (int t = wave; t < 16 * NH; t += 4) {
        int lr   = (NH == 2) ? (t >> 1) : t;
        int half = (NH == 2) ? (t & 1) : 0;
        int node = r0 + lr;
        int off = half * 64 + lane;

        unsigned v = xu[(size_t)node * U2 + off];
        float a0 = bf2f((unsigned short)(v & 0xffff));
        float a1 = bf2f((unsigned short)(v >> 16));

        int dg = min(deg[node], ELL_W);
        const unsigned short* row = ell + (size_t)node * ELL_W;
        int j = 0;
        for (; j + 16 <= dg; j += 16) {
            short8 iA = *(const short8*)(row + j);
            short8 iB = *(const short8*)(row + j + 8);
            unsigned vv[16];
#pragma unroll
            for (int q = 0; q < 8; ++q)
                vv[q] = xu[(size_t)(unsigned short)iA[q] * U2 + off];
#pragma unroll
            for (int q = 0; q < 8; ++q)
                vv[8 + q] = xu[(size_t)(unsigned short)iB[q] * U2 + off];
#pragma unroll
            for (int q = 0; q < 16; ++q) {
                a0 += bf2f((unsigned short)(vv[q] & 0xffff));
                a1 += bf2f((unsigned short)(vv[q] >> 16));
            }
        }
        for (; j + 4 <= dg; j += 4) {
            ushort4 sA = *(const ushort4*)(row + j);
            unsigned v0 = xu[(size_t)sA.x * U2 + off];
            unsigned v1 = xu[(size_t)sA.y * U2 + off];
            unsigned v2 = xu[(size_t)sA.z * U2 + off];
            unsigned v3 = xu[(size_t)sA.w * U2 + off];
            a0 += (bf2f((unsigned short)(v0 & 0xffff)) + bf2f((unsigned short)(v1 & 0xffff))) +
                  (bf2f((unsigned short)(v2 & 0xffff)) + bf2f((unsigned short)(v3 & 0xffff)));
            a1 += (bf2f((unsigned short)(v0 >> 16)) + bf2f((unsigned short)(v1 >> 16))) +
                  (bf2f((unsigned short)(v2 >> 16)) + bf2f((unsigned short)(v3 >> 16)));
        }
        for (; j < dg; ++j) {
            unsigned vv = xu[(size_t)row[j] * U2 + off];
            a0 += bf2f((unsigned short)(vv & 0xffff));
            a1 += bf2f((unsigned short)(vv >> 16));
        }
        aggU[lr * LPAU + off] = (unsigned)f2bf(a0) | ((unsigned)f2bf(a1) << 16);
    }
    __syncthreads();

    int lrow = lane & 15;
    int lkg = lane >> 4;
    int n0 = wave * 64;   // wave owns one 64-col quarter in both stages

    // ---- Stage 1: hid = ReLU(agg @ WtA + bA), A from LDS ----
    {
        const short8* Bp = (const short8*)(WtA + (size_t)(n0 + lrow) * K1 + lkg * 8);
        f32x4 acc[4] = {};
#pragma unroll
        for (int ks = 0; ks < KSTEPS; ++ks) {
            short8 a = *(const short8*)&agg[lrow * LPA + ks * 32 + lkg * 8];
            short8 b0 = Bp[ks * 4 + 0 * 2 * K1];
            short8 b1 = Bp[ks * 4 + 1 * 2 * K1];
            short8 b2 = Bp[ks * 4 + 2 * 2 * K1];
            short8 b3 = Bp[ks * 4 + 3 * 2 * K1];
            acc[0] = __builtin_amdgcn_mfma_f32_16x16x32_bf16(a, b0, acc[0], 0, 0, 0);
            acc[1] = __builtin_amdgcn_mfma_f32_16x16x32_bf16(a, b1, acc[1], 0, 0, 0);
            acc[2] = __builtin_amdgcn_mfma_f32_16x16x32_bf16(a, b2, acc[2], 0, 0, 0);
            acc[3] = __builtin_amdgcn_mfma_f32_16x16x32_bf16(a, b3, acc[3], 0, 0, 0);
        }
        int rowb = lkg * 4;
#pragma unroll
        for (int nt = 0; nt < 4; ++nt) {
            int c = n0 + nt * 16 + lrow;
            float bv = biasA[c];
#pragma unroll
            for (int r = 0; r < 4; ++r) {
                float v = fmaxf(acc[nt][r] + bv, 0.f);
                hid[(rowb + r) * 264 + c] = f2bf(v);
            }
        }
    }
    __syncthreads();

    // ---- Stage 2: out = hid @ WtB + bB ----
    {
        const short8* Bp = (const short8*)(WtB + (size_t)(n0 + lrow) * 256 + lkg * 8);
        f32x4 acc[4] = {};
#pragma unroll
        for (int ks = 0; ks < 8; ++ks) {
            short8 a = *(const short8*)&hid[lrow * 264 + ks * 32 + lkg * 8];
            short8 b0 = Bp[ks * 4 + 0 * 2 * 256];
            short8 b1 = Bp[ks * 4 + 1 * 2 * 256];
            short8 b2 = Bp[ks * 4 + 2 * 2 * 256];
            short8 b3 = Bp[ks * 4 + 3 * 2 * 256];
            acc[0] = __builtin_amdgcn_mfma_f32_16x16x32_bf16(a, b0, acc[0], 0, 0, 0);
            acc[1] = __builtin_amdgcn_mfma_f32_16x16x32_bf16(a, b1, acc[1], 0, 0, 0);
            acc[2] = __builtin_amdgcn_mfma_f32_16x16x32_bf16(a, b2, acc[2], 0, 0, 0);
            acc[3] = __builtin_amdgcn_mfma_f32_16x16x32_bf16(a, b3, acc[3], 0, 0, 0);
        }
        int orow = r0 + lkg * 4;
#pragma unroll
        for (int nt = 0; nt < 4; ++nt) {
            int c = n0 + nt * 16 + lrow;
            float bv = biasB[c];
#pragma unroll
            for (int r = 0; r < 4; ++r) {
                float v = acc[nt][r] + bv;
                if (RELU2) v = fmaxf(v, 0.f);
                if (F32OUT)
                    ((float*)Cout)[(size_t)(orow + r) * 256 + c] = v;
                else
                    ((unsigned short*)Cout)[(size_t)(orow + r) * 256 + c] = f2bf(v);
            }
        }
    }
}

// ---------------------------------------------------------------------------
extern "C" void kernel_launch(void* const* d_in, const int* in_sizes, int n_in,
                              void* d_out, int out_size, void* d_ws, size_t ws_size,
                              hipStream_t stream) {
    const float* x   = (const float*)d_in[0];
    const int*   ei  = (const int*)d_in[1];
    const int*   src = ei;
    const int*   dst = ei + N_EDGES;
    const float* W0a = (const float*)d_in[2];
    const float* b0a = (const float*)d_in[3];
    const float* W0b = (const float*)d_in[4];
    const float* b0b = (const float*)d_in[5];
    const float* W1a = (const float*)d_in[6];
    const float* b1a = (const float*)d_in[7];
    const float* W1b = (const float*)d_in[8];
    const float* b1b = (const float*)d_in[9];
    const float* W2a = (const float*)d_in[10];
    const float* b2a = (const float*)d_in[11];
    const float* W2b = (const float*)d_in[12];
    const float* b2b = (const float*)d_in[13];

    char* ws = (char*)d_ws;
    size_t off = 0;
    auto alloc = [&](size_t bytes) {
        void* p = ws + off;
        off += (bytes + 255) & ~(size_t)255;
        return p;
    };
    unsigned short* xb    = (unsigned short*)alloc((size_t)N_NODES * 128 * 2);
    unsigned short* H0    = (unsigned short*)alloc((size_t)N_NODES * 256 * 2);
    unsigned short* H1    = (unsigned short*)alloc((size_t)N_NODES * 256 * 2);
    unsigned short* Wt0a  = (unsigned short*)alloc(256 * 128 * 2);
    unsigned short* Wt0b  = (unsigned short*)alloc(256 * 256 * 2);
    unsigned short* Wt1a  = (unsigned short*)alloc(256 * 256 * 2);
    unsigned short* Wt1b  = (unsigned short*)alloc(256 * 256 * 2);
    unsigned short* Wt2a  = (unsigned short*)alloc(256 * 256 * 2);
    unsigned short* Wt2b  = (unsigned short*)alloc(256 * 256 * 2);
    int*            deg   = (int*)alloc(N_NODES * 4);
    unsigned short* ell   = (unsigned short*)alloc((size_t)N_NODES * ELL_W * 2);
    int*            gCur  = (int*)alloc(NB * 4);
    unsigned*       gBkt  = (unsigned*)alloc((size_t)NB * BCAP * 4);

    int fusedBlocks = N_NODES / 16;   // 625

    // ---- prep: zero cursors + x->bf16 + weight transpose/convert (1 dispatch)
    WList wl;
    wl.src[0] = W0a; wl.dst[0] = Wt0a; wl.K[0] = 128;
    wl.src[1] = W0b; wl.dst[1] = Wt0b; wl.K[1] = 256;
    wl.src[2] = W1a; wl.dst[2] = Wt1a; wl.K[2] = 256;
    wl.src[3] = W1b; wl.dst[3] = Wt1b; wl.K[3] = 256;
    wl.src[4] = W2a; wl.dst[4] = Wt2a; wl.K[4] = 256;
    wl.src[5] = W2b; wl.dst[5] = Wt2b; wl.K[5] = 256;
    int totalW = 0;
    for (int i = 0; i < 6; ++i) { wl.off[i] = totalW; totalW += wl.K[i] * 256; }
    wl.off[6] = totalW;
    int n4 = N_NODES * 128 / 4;
    int prepTasks = n4 + totalW;
    prep_kernel<<<(prepTasks + 255) / 256, 256, 0, stream>>>(
        (const float4*)x, (ushort4*)xb, n4, wl, totalW, gCur);

    // ---- ELL build ----
    bin_edges<<<(N_EDGES + CHUNK - 1) / CHUNK, 256, 0, stream>>>(src, dst, gCur, gBkt);
    build_ell<<<NB, 256, 0, stream>>>(gBkt, gCur, ell, deg);

    // ---- Layer 0 (C_in = 128): xb -> H0 ----
    fused_gin<128, true, false><<<fusedBlocks, 256, 0, stream>>>(
        (const unsigned*)xb, ell, deg, Wt0a, b0a, Wt0b, b0b, H0);
    // ---- Layer 1 (C = 256): H0 -> H1 ----
    fused_gin<256, true, false><<<fusedBlocks, 256, 0, stream>>>(
        (const unsigned*)H0, ell, deg, Wt1a, b1a, Wt1b, b1b, H1);
    // ---- Layer 2 (C = 256): H1 -> d_out (fp32, no ReLU) ----
    fused_gin<256, false, true><<<fusedBlocks, 256, 0, stream>>>(
        (const unsigned*)H1, ell, deg, Wt2a, b2a, Wt2b, b2b, d_out);
}